// Round 1
// baseline (2019.367 us; speedup 1.0000x reference)
//
#include <hip/hip_runtime.h>
#include <hip/hip_bf16.h>
#include <stdint.h>

// MoE FFN (DeepSeek-style): sigmoid router w/ group-limited greedy top-8 of 64,
// SwiGLU experts (1024->512->1024) + shared expert (1024->2048->1024).
// B=1 T=4096 C=1024 E=64 K=8 G=8 TG=4 H=512 HS=2048. All inputs fp32.
// Strategy: bf16 MFMA (16x16x32) for all GEMMs, fp32 accumulate.
// Threshold is 2% of absmax -> bf16 is safe.

#define S_TOK 4096
#define C_DIM 1024
#define E_NUM 64
#define K_TOP 8
#define H_DIM 512
#define HS_DIM 2048
#define ROWS_TOTAL (S_TOK * K_TOP)   // 32768

typedef __attribute__((ext_vector_type(8))) short short8;
typedef __attribute__((ext_vector_type(4))) float f32x4;

static __device__ __forceinline__ short f2bf(float f) {
    union { float f; uint32_t u; } v; v.f = f;
    uint32_t u = v.u;
    u += 0x7fffu + ((u >> 16) & 1u);   // RNE
    return (short)(u >> 16);
}
static __device__ __forceinline__ float bfbits2f(uint32_t lo16) {
    union { uint32_t u; float f; } v; v.u = lo16 << 16;
    return v.f;
}

// ---------------- router ----------------
// one wave (64 threads) per token; lane e computes score for expert e.
__global__ void router_k(const float* __restrict__ x, const float* __restrict__ rw,
                         const float* __restrict__ ebias,
                         int* __restrict__ topk_idx, float* __restrict__ topk_w,
                         int* __restrict__ counts) {
    int t = blockIdx.x;
    __shared__ float xs[C_DIM];
    __shared__ float sc[E_NUM];
    __shared__ float sb[E_NUM];
    int lane = threadIdx.x;  // 0..63
    for (int i = lane; i < C_DIM; i += 64) xs[i] = x[(size_t)t * C_DIM + i];
    __syncthreads();
    float acc = 0.f;
    const float* wrow = rw + (size_t)lane * C_DIM;
    #pragma unroll 4
    for (int i = 0; i < C_DIM; i += 4) {
        float4 w4 = *(const float4*)(wrow + i);
        acc += xs[i] * w4.x + xs[i+1] * w4.y + xs[i+2] * w4.z + xs[i+3] * w4.w;
    }
    float s = 1.f / (1.f + __expf(-acc));   // sigmoid
    sc[lane] = s;
    sb[lane] = s + ebias[lane];
    __syncthreads();
    if (lane == 0) {
        // per-group score: sum of top-2 biased scores in each group of 8
        float grp[8];
        for (int g = 0; g < 8; g++) {
            float m1 = -1e30f, m2 = -1e30f;
            for (int j = 0; j < 8; j++) {
                float v = sb[g * 8 + j];
                if (v > m1) { m2 = m1; m1 = v; } else if (v > m2) { m2 = v; }
            }
            grp[g] = m1 + m2;
        }
        // top-4 groups (strict > keeps lowest index on ties, matching lax.top_k)
        unsigned gsel = 0;
        for (int k = 0; k < 4; k++) {
            float best = -1e30f; int bi = 0;
            for (int g = 0; g < 8; g++)
                if (!((gsel >> g) & 1) && grp[g] > best) { best = grp[g]; bi = g; }
            gsel |= 1u << bi;
        }
        // top-8 experts among selected groups
        unsigned long long taken = 0ull;
        int idx[8]; float wv[8]; float wsum = 0.f;
        for (int k = 0; k < 8; k++) {
            float best = -1e30f; int bi = 0;
            for (int e = 0; e < 64; e++) {
                if (!((gsel >> (e >> 3)) & 1)) continue;
                if ((taken >> e) & 1) continue;
                if (sb[e] > best) { best = sb[e]; bi = e; }
            }
            taken |= 1ull << bi;
            idx[k] = bi; wv[k] = sc[bi]; wsum += sc[bi];
        }
        float inv = 1.f / (wsum + 1e-20f);
        for (int k = 0; k < 8; k++) {
            topk_idx[t * 8 + k] = idx[k];
            topk_w[t * 8 + k] = wv[k] * inv;
            atomicAdd(&counts[idx[k]], 1);
        }
    }
}

__global__ void zero_counts_k(int* counts) { counts[threadIdx.x] = 0; }

__global__ void scan_k(const int* __restrict__ counts, int* __restrict__ base,
                       int* __restrict__ cursor) {
    if (threadIdx.x == 0) {
        int s = 0;
        for (int e = 0; e < E_NUM; e++) { base[e] = s; cursor[e] = s; s += counts[e]; }
    }
}

__global__ void scatter_k(const int* __restrict__ topk_idx, const float* __restrict__ topk_w,
                          int* __restrict__ cursor, int* __restrict__ row_token,
                          float* __restrict__ row_wgt) {
    int i = blockIdx.x * blockDim.x + threadIdx.x;  // 0..32767
    int e = topk_idx[i];
    int pos = atomicAdd(&cursor[e], 1);
    row_token[pos] = i >> 3;
    row_wgt[pos] = topk_w[i];
}

// ---------------- GEMM ----------------
// C[M,N] = A[M,K] @ B[K,N], row-major. 128x128 tile, BK=32, 256 thr (4 waves,
// each wave a 64x64 quadrant of 4x4 16x16x32 bf16 MFMAs).
// ABF16: A is bf16 in ws (else fp32 global, converted in staging)
// GROUPED: blockIdx.z = expert; rows = counts[e] at base[e]; B += e*K*N
// GATHER: A row r -> x[row_token[base+r]]   (fp32 path only)
// EPI: 0 = store fp32 C, 1 = store bf16 C, 2 = scale by row_wgt + atomicAdd to Outp[token]
template<bool ABF16, bool GROUPED, bool GATHER, int EPI>
__global__ __launch_bounds__(256)
void gemm_k(const void* __restrict__ Aptr, const float* __restrict__ Bmat,
            void* __restrict__ Cptr, float* __restrict__ Outp,
            int M, int N, int K,
            const int* __restrict__ counts, const int* __restrict__ base,
            const int* __restrict__ row_token, const float* __restrict__ row_wgt) {
    int e = GROUPED ? blockIdx.z : 0;
    int Mrows = GROUPED ? counts[e] : M;
    int m0 = blockIdx.y * 128;
    if (m0 >= Mrows) return;
    int n0 = blockIdx.x * 128;
    int rowbase = GROUPED ? base[e] : 0;
    const float* B = Bmat + (GROUPED ? (size_t)e * K * N : 0);

    // stride 40 bf16 (80B): +8 pad keeps ds_read_b128 16B-aligned, <=2-way conflicts
    __shared__ short As[128 * 40];
    __shared__ short Bs[128 * 40];

    int tid = threadIdx.x;
    int lane = tid & 63;
    int w = tid >> 6;
    int wr = w >> 1, wc = w & 1;
    int quad = lane >> 4, l16 = lane & 15;

    f32x4 acc[4][4] = {};

    for (int k0 = 0; k0 < K; k0 += 32) {
        // ---- stage A (128 rows x 32 cols) ----
        if (ABF16) {
            const short* Ab = (const short*)Aptr;
            #pragma unroll
            for (int i = 0; i < 2; i++) {
                int idx = tid + 256 * i;
                int r = idx >> 2, c8 = idx & 3;
                int row = m0 + r;
                uint4 v = {0u, 0u, 0u, 0u};
                if (row < Mrows)
                    v = *(const uint4*)(Ab + (size_t)(rowbase + row) * K + k0 + c8 * 8);
                *(uint4*)&As[r * 40 + c8 * 8] = v;
            }
        } else {
            const float* Af = (const float*)Aptr;
            #pragma unroll
            for (int i = 0; i < 4; i++) {
                int idx = tid + 256 * i;
                int r = idx >> 3, c4 = idx & 7;
                int row = m0 + r;
                float4 v = {0.f, 0.f, 0.f, 0.f};
                if (row < Mrows) {
                    size_t arow = GATHER ? (size_t)row_token[rowbase + row] : (size_t)row;
                    v = *(const float4*)(Af + arow * K + k0 + c4 * 4);
                }
                short tmp[4] = { f2bf(v.x), f2bf(v.y), f2bf(v.z), f2bf(v.w) };
                *(uint2*)&As[r * 40 + c4 * 4] = *(uint2*)tmp;
            }
        }
        // ---- stage B (32 rows x 128 cols) transposed -> Bs[n][k] ----
        #pragma unroll
        for (int i = 0; i < 4; i++) {
            int idx = tid + 256 * i;
            int kk = idx >> 5, c4 = idx & 31;
            float4 v = *(const float4*)(B + (size_t)(k0 + kk) * N + n0 + c4 * 4);
            Bs[(c4 * 4 + 0) * 40 + kk] = f2bf(v.x);
            Bs[(c4 * 4 + 1) * 40 + kk] = f2bf(v.y);
            Bs[(c4 * 4 + 2) * 40 + kk] = f2bf(v.z);
            Bs[(c4 * 4 + 3) * 40 + kk] = f2bf(v.w);
        }
        __syncthreads();
        // ---- fragments + MFMA ----
        short8 a[4], b[4];
        #pragma unroll
        for (int i = 0; i < 4; i++) {
            int m = wr * 64 + i * 16 + l16;
            a[i] = *(const short8*)&As[m * 40 + quad * 8];
        }
        #pragma unroll
        for (int j = 0; j < 4; j++) {
            int n = wc * 64 + j * 16 + l16;
            b[j] = *(const short8*)&Bs[n * 40 + quad * 8];
        }
        #pragma unroll
        for (int i = 0; i < 4; i++)
            #pragma unroll
            for (int j = 0; j < 4; j++)
                acc[i][j] = __builtin_amdgcn_mfma_f32_16x16x32_bf16(a[i], b[j], acc[i][j], 0, 0, 0);
        __syncthreads();
    }
    // ---- epilogue ----
    #pragma unroll
    for (int i = 0; i < 4; i++) {
        #pragma unroll
        for (int r = 0; r < 4; r++) {
            int m = wr * 64 + i * 16 + quad * 4 + r;
            int row = m0 + m;
            if (row >= Mrows) continue;
            int grow = rowbase + row;
            int tok = 0; float scl = 0.f;
            if (EPI == 2) { tok = row_token[grow]; scl = row_wgt[grow]; }
            #pragma unroll
            for (int j = 0; j < 4; j++) {
                int n = n0 + wc * 64 + j * 16 + l16;
                float vv = acc[i][j][r];
                if (EPI == 0)      ((float*)Cptr)[(size_t)grow * N + n] = vv;
                else if (EPI == 1) ((short*)Cptr)[(size_t)grow * N + n] = f2bf(vv);
                else               atomicAdd(&Outp[(size_t)tok * N + n], vv * scl);
            }
        }
    }
}

// ---------------- SiLU(g)*u elementwise (bf16 in/out, 8 elems/thread) ----------------
__global__ void silu_mul_k(const short* __restrict__ G, const short* __restrict__ U,
                           short* __restrict__ H, int n8) {
    int i = blockIdx.x * blockDim.x + threadIdx.x;
    if (i >= n8) return;
    uint4 g4 = ((const uint4*)G)[i];
    uint4 u4 = ((const uint4*)U)[i];
    uint32_t* gp = (uint32_t*)&g4;
    uint32_t* up = (uint32_t*)&u4;
    uint4 h4;
    uint32_t* hp = (uint32_t*)&h4;
    #pragma unroll
    for (int w = 0; w < 4; w++) {
        float g0 = bfbits2f(gp[w] & 0xffffu), g1 = bfbits2f(gp[w] >> 16);
        float u0 = bfbits2f(up[w] & 0xffffu), u1 = bfbits2f(up[w] >> 16);
        float h0 = (g0 / (1.f + __expf(-g0))) * u0;
        float h1 = (g1 / (1.f + __expf(-g1))) * u1;
        uint32_t b0 = (uint32_t)(unsigned short)f2bf(h0);
        uint32_t b1 = (uint32_t)(unsigned short)f2bf(h1);
        hp[w] = b0 | (b1 << 16);
    }
    ((uint4*)H)[i] = h4;
}

// ---------------- launch ----------------
extern "C" void kernel_launch(void* const* d_in, const int* in_sizes, int n_in,
                              void* d_out, int out_size, void* d_ws, size_t ws_size,
                              hipStream_t stream) {
    const float* x        = (const float*)d_in[0];
    const float* router_w = (const float*)d_in[1];
    const float* e_bias   = (const float*)d_in[2];
    const float* gate_w   = (const float*)d_in[3];
    const float* up_w     = (const float*)d_in[4];
    const float* down_w   = (const float*)d_in[5];
    const float* sh_gate  = (const float*)d_in[6];
    const float* sh_up    = (const float*)d_in[7];
    const float* sh_down  = (const float*)d_in[8];
    float* out = (float*)d_out;
    char* ws = (char*)d_ws;

    // ws layout (~97 MB): control block + routed row maps + aliased G/U/H bf16 bufs
    int*   counts    = (int*)(ws);
    int*   base      = (int*)(ws + 256);
    int*   cursor    = (int*)(ws + 512);
    int*   topk_idx  = (int*)(ws + 1024);
    float* topk_w    = (float*)(ws + 1024 + 131072);
    int*   row_token = (int*)(ws + 1024 + 2 * 131072);
    float* row_wgt   = (float*)(ws + 1024 + 3 * 131072);
    short* Gbuf = (short*)(ws + (1u << 20));                   // 32 MB
    short* Ubuf = (short*)(ws + (1u << 20) + (32u << 20));     // 32 MB
    short* Hbuf = (short*)(ws + (1u << 20) + (64u << 20));     // 32 MB

    // ---- routing ----
    zero_counts_k<<<1, 64, 0, stream>>>(counts);
    router_k<<<S_TOK, 64, 0, stream>>>(x, router_w, e_bias, topk_idx, topk_w, counts);
    scan_k<<<1, 64, 0, stream>>>(counts, base, cursor);
    scatter_k<<<ROWS_TOTAL / 256, 256, 0, stream>>>(topk_idx, topk_w, cursor, row_token, row_wgt);

    // ---- shared expert ----
    gemm_k<false, false, false, 1><<<dim3(HS_DIM / 128, S_TOK / 128, 1), 256, 0, stream>>>(
        x, sh_gate, Gbuf, nullptr, S_TOK, HS_DIM, C_DIM, nullptr, nullptr, nullptr, nullptr);
    gemm_k<false, false, false, 1><<<dim3(HS_DIM / 128, S_TOK / 128, 1), 256, 0, stream>>>(
        x, sh_up, Ubuf, nullptr, S_TOK, HS_DIM, C_DIM, nullptr, nullptr, nullptr, nullptr);
    {
        int n8 = S_TOK * HS_DIM / 8;
        silu_mul_k<<<(n8 + 255) / 256, 256, 0, stream>>>(Gbuf, Ubuf, Hbuf, n8);
    }
    gemm_k<true, false, false, 0><<<dim3(C_DIM / 128, S_TOK / 128, 1), 256, 0, stream>>>(
        Hbuf, sh_down, out, nullptr, S_TOK, C_DIM, HS_DIM, nullptr, nullptr, nullptr, nullptr);

    // ---- routed experts (grouped GEMMs; max 32 M-tiles per expert) ----
    gemm_k<false, true, true, 1><<<dim3(H_DIM / 128, 32, E_NUM), 256, 0, stream>>>(
        x, gate_w, Gbuf, nullptr, 0, H_DIM, C_DIM, counts, base, row_token, row_wgt);
    gemm_k<false, true, true, 1><<<dim3(H_DIM / 128, 32, E_NUM), 256, 0, stream>>>(
        x, up_w, Ubuf, nullptr, 0, H_DIM, C_DIM, counts, base, row_token, row_wgt);
    {
        int n8 = ROWS_TOTAL * H_DIM / 8;
        silu_mul_k<<<(n8 + 255) / 256, 256, 0, stream>>>(Gbuf, Ubuf, Hbuf, n8);
    }
    gemm_k<true, true, false, 2><<<dim3(C_DIM / 128, 32, E_NUM), 256, 0, stream>>>(
        Hbuf, down_w, nullptr, out, 0, C_DIM, H_DIM, counts, base, row_token, row_wgt);
}

// Round 2
// 1185.874 us; speedup vs baseline: 1.7029x; 1.7029x over previous
//
#include <hip/hip_runtime.h>
#include <hip/hip_bf16.h>
#include <stdint.h>

// MoE FFN: sigmoid router (group-limited greedy top-8 of 64), SwiGLU experts
// (1024->512->1024) + shared expert (1024->2048->1024). All inputs fp32.
// R2: prepass converts x + all weights to bf16 (weights transposed to [N][K]);
// GEMMs use m97 structure: global_load_lds width-16 staging, unpadded 64B LDS
// rows, ds_read_b128 fragments, 16x16x32 bf16 MFMA. Gate+up+SiLU fused.

#define S_TOK 4096
#define C_DIM 1024
#define E_NUM 64
#define H_DIM 512
#define HS_DIM 2048
#define ROWS_TOTAL (S_TOK * 8)

typedef __attribute__((ext_vector_type(8))) short short8;
typedef __attribute__((ext_vector_type(4))) float f32x4;

static __device__ __forceinline__ unsigned short f2bf(float f) {
    union { float f; uint32_t u; } v; v.f = f;
    uint32_t u = v.u;
    u += 0x7fffu + ((u >> 16) & 1u);   // RNE
    return (unsigned short)(u >> 16);
}

static __device__ __forceinline__ void gl2lds16(const void* g, void* l) {
    __builtin_amdgcn_global_load_lds(
        (const __attribute__((address_space(1))) uint32_t*)g,
        (__attribute__((address_space(3))) uint32_t*)l, 16, 0, 0);
}

// ---------------- router (unchanged from R1, passed) ----------------
__global__ void router_k(const float* __restrict__ x, const float* __restrict__ rw,
                         const float* __restrict__ ebias,
                         int* __restrict__ topk_idx, float* __restrict__ topk_w,
                         int* __restrict__ counts) {
    int t = blockIdx.x;
    __shared__ float xs[C_DIM];
    __shared__ float sc[E_NUM];
    __shared__ float sb[E_NUM];
    int lane = threadIdx.x;
    for (int i = lane; i < C_DIM; i += 64) xs[i] = x[(size_t)t * C_DIM + i];
    __syncthreads();
    float acc = 0.f;
    const float* wrow = rw + (size_t)lane * C_DIM;
    #pragma unroll 4
    for (int i = 0; i < C_DIM; i += 4) {
        float4 w4 = *(const float4*)(wrow + i);
        acc += xs[i] * w4.x + xs[i+1] * w4.y + xs[i+2] * w4.z + xs[i+3] * w4.w;
    }
    float s = 1.f / (1.f + __expf(-acc));
    sc[lane] = s;
    sb[lane] = s + ebias[lane];
    __syncthreads();
    if (lane == 0) {
        float grp[8];
        for (int g = 0; g < 8; g++) {
            float m1 = -1e30f, m2 = -1e30f;
            for (int j = 0; j < 8; j++) {
                float v = sb[g * 8 + j];
                if (v > m1) { m2 = m1; m1 = v; } else if (v > m2) { m2 = v; }
            }
            grp[g] = m1 + m2;
        }
        unsigned gsel = 0;
        for (int k = 0; k < 4; k++) {
            float best = -1e30f; int bi = 0;
            for (int g = 0; g < 8; g++)
                if (!((gsel >> g) & 1) && grp[g] > best) { best = grp[g]; bi = g; }
            gsel |= 1u << bi;
        }
        unsigned long long taken = 0ull;
        int idx[8]; float wv[8]; float wsum = 0.f;
        for (int k = 0; k < 8; k++) {
            float best = -1e30f; int bi = 0;
            for (int e = 0; e < 64; e++) {
                if (!((gsel >> (e >> 3)) & 1)) continue;
                if ((taken >> e) & 1) continue;
                if (sb[e] > best) { best = sb[e]; bi = e; }
            }
            taken |= 1ull << bi;
            idx[k] = bi; wv[k] = sc[bi]; wsum += sc[bi];
        }
        float inv = 1.f / (wsum + 1e-20f);
        for (int k = 0; k < 8; k++) {
            topk_idx[t * 8 + k] = idx[k];
            topk_w[t * 8 + k] = wv[k] * inv;
            atomicAdd(&counts[idx[k]], 1);
        }
    }
}

__global__ void zero_counts_k(int* counts) { counts[threadIdx.x] = 0; }

__global__ void scan_k(const int* __restrict__ counts, int* __restrict__ base,
                       int* __restrict__ cursor) {
    if (threadIdx.x == 0) {
        int s = 0;
        for (int e = 0; e < E_NUM; e++) { base[e] = s; cursor[e] = s; s += counts[e]; }
    }
}

__global__ void scatter_k(const int* __restrict__ topk_idx, const float* __restrict__ topk_w,
                          int* __restrict__ cursor, int* __restrict__ row_token,
                          float* __restrict__ row_wgt) {
    int i = blockIdx.x * blockDim.x + threadIdx.x;
    int e = topk_idx[i];
    int pos = atomicAdd(&cursor[e], 1);
    row_token[pos] = i >> 3;
    row_wgt[pos] = topk_w[i];
}

// ---------------- prepass: fp32 -> bf16 elementwise (x) ----------------
__global__ void cvt_bf16_k(const float* __restrict__ in, unsigned short* __restrict__ out, int n8) {
    int i = blockIdx.x * blockDim.x + threadIdx.x;
    if (i >= n8) return;
    float4 v0 = ((const float4*)in)[2 * i];
    float4 v1 = ((const float4*)in)[2 * i + 1];
    unsigned short t[8] = { f2bf(v0.x), f2bf(v0.y), f2bf(v0.z), f2bf(v0.w),
                            f2bf(v1.x), f2bf(v1.y), f2bf(v1.z), f2bf(v1.w) };
    ((uint4*)out)[i] = *(uint4*)t;
}

// ---------------- prepass: fp32 [R][C] -> bf16 [C][R], batched over z ----------------
#define TP 69   // pad-69 fp32 rows: write banks 8-way, read banks 2-way (free)
__global__ __launch_bounds__(256)
void transpose_k(const float* __restrict__ in, unsigned short* __restrict__ out, int R, int C) {
    size_t bofs = (size_t)blockIdx.z * R * C;
    in += bofs; out += bofs;
    int r0 = blockIdx.y * 64, c0 = blockIdx.x * 64;
    __shared__ float T[64 * TP];   // T[c][r]
    int t = threadIdx.x;
    int cg = t & 15, rg = t >> 4;  // 4x4 subtile per thread
    #pragma unroll
    for (int ii = 0; ii < 4; ii++) {
        float4 v = *(const float4*)(in + (size_t)(r0 + rg * 4 + ii) * C + c0 + cg * 4);
        T[(cg * 4 + 0) * TP + rg * 4 + ii] = v.x;
        T[(cg * 4 + 1) * TP + rg * 4 + ii] = v.y;
        T[(cg * 4 + 2) * TP + rg * 4 + ii] = v.z;
        T[(cg * 4 + 3) * TP + rg * 4 + ii] = v.w;
    }
    __syncthreads();
    int n = t >> 2, ks = (t & 3) * 16;
    unsigned short h[16];
    #pragma unroll
    for (int u = 0; u < 16; u++) h[u] = f2bf(T[n * TP + ks + u]);
    unsigned short* op = out + (size_t)(c0 + n) * R + r0 + ks;
    *(uint4*)op = *(uint4*)&h[0];
    *(uint4*)(op + 8) = *(uint4*)&h[8];
}

// ---------------- GEMM: C[M,N] = A[M,K] @ Bt[N,K]^T, bf16 in, fp32 acc ----------------
// 128x128 tile, BK=32, 256 thr (4 waves = 2x2 quadrants of 4x4 16x16x32 MFMA).
// FUSED: two B matrices (gate+up), epilogue h = silu(g)*u -> bf16 store
// GATHER: A row via row_token; GROUPED: blockIdx.z = expert
// EPI: 0 = fused silu bf16 store, 1 = fp32 store, 2 = scale + atomicAdd fp32
template<bool FUSED, bool GATHER, bool GROUPED, int EPI>
__global__ __launch_bounds__(256, 2)
void gemm2_k(const short* __restrict__ A, const short* __restrict__ B1t,
             const short* __restrict__ B2t, void* __restrict__ Cout,
             int M, int N, int K,
             const int* __restrict__ counts, const int* __restrict__ base,
             const int* __restrict__ row_token, const float* __restrict__ row_wgt) {
    int e = GROUPED ? blockIdx.z : 0;
    int Mrows = GROUPED ? counts[e] : M;
    int m0 = blockIdx.y * 128;
    if (m0 >= Mrows) return;
    int n0 = blockIdx.x * 128;
    int rowbase = GROUPED ? base[e] : 0;
    const short* B1 = B1t + (GROUPED ? (size_t)e * N * K : 0) + (size_t)n0 * K;
    const short* B2 = FUSED ? (B2t + (GROUPED ? (size_t)e * N * K : 0) + (size_t)n0 * K) : nullptr;

    // unpadded 64B rows (m97 layout: global_load_lds-compatible, b128-clean)
    __shared__ short As[128 * 32];
    __shared__ short Bs1[128 * 32];
    __shared__ short Bs2[FUSED ? 128 * 32 : 8];

    int tid = threadIdx.x;
    int lane = tid & 63, w = tid >> 6;
    int wr = w >> 1, wc = w & 1;
    int quad = lane >> 4, l16 = lane & 15;
    int sr = lane >> 2, sc = lane & 3;   // staging: row-in-16-group, 16B chunk

    // per-lane global row pointers (k-invariant)
    const short* aptr[2];
    const short* b1ptr[2];
    const short* b2ptr[2];
    #pragma unroll
    for (int i = 0; i < 2; i++) {
        int row = w * 32 + i * 16 + sr;                 // 0..127 within tile
        int mrow = m0 + row;
        int cl = mrow < Mrows ? mrow : (Mrows - 1);     // clamp (garbage rows unused)
        size_t arow;
        if (GATHER)       arow = (size_t)row_token[rowbase + cl];
        else if (GROUPED) arow = (size_t)(rowbase + cl);
        else              arow = (size_t)mrow;
        aptr[i] = A + arow * K + sc * 8;
        b1ptr[i] = B1 + (size_t)row * K + sc * 8;
        if (FUSED) b2ptr[i] = B2 + (size_t)row * K + sc * 8;
    }

    f32x4 acc1[4][4] = {};
    f32x4 acc2[4][4] = {};

    for (int k0 = 0; k0 < K; k0 += 32) {
        #pragma unroll
        for (int i = 0; i < 2; i++) {
            int lb = (w * 32 + i * 16) * 32;   // shorts; lane writes +lane*16B
            gl2lds16(aptr[i], &As[lb]);   aptr[i] += 32;
            gl2lds16(b1ptr[i], &Bs1[lb]); b1ptr[i] += 32;
            if (FUSED) { gl2lds16(b2ptr[i], &Bs2[lb]); b2ptr[i] += 32; }
        }
        __syncthreads();
        short8 a[4], b1[4], b2[4];
        #pragma unroll
        for (int i = 0; i < 4; i++)
            a[i] = *(const short8*)&As[(wr * 64 + i * 16 + l16) * 32 + quad * 8];
        #pragma unroll
        for (int j = 0; j < 4; j++) {
            b1[j] = *(const short8*)&Bs1[(wc * 64 + j * 16 + l16) * 32 + quad * 8];
            if (FUSED)
                b2[j] = *(const short8*)&Bs2[(wc * 64 + j * 16 + l16) * 32 + quad * 8];
        }
        #pragma unroll
        for (int i = 0; i < 4; i++)
            #pragma unroll
            for (int j = 0; j < 4; j++) {
                acc1[i][j] = __builtin_amdgcn_mfma_f32_16x16x32_bf16(a[i], b1[j], acc1[i][j], 0, 0, 0);
                if (FUSED)
                    acc2[i][j] = __builtin_amdgcn_mfma_f32_16x16x32_bf16(a[i], b2[j], acc2[i][j], 0, 0, 0);
            }
        __syncthreads();
    }

    // epilogue: D row = quad*4+rr, col = l16
    #pragma unroll
    for (int i = 0; i < 4; i++) {
        #pragma unroll
        for (int rr = 0; rr < 4; rr++) {
            int row = m0 + wr * 64 + i * 16 + quad * 4 + rr;
            if (row >= Mrows) continue;
            size_t orow = GROUPED ? (size_t)(rowbase + row) : (size_t)row;
            int tok = 0; float scl = 0.f;
            if (EPI == 2) { tok = row_token[rowbase + row]; scl = row_wgt[rowbase + row]; }
            #pragma unroll
            for (int j = 0; j < 4; j++) {
                int n = n0 + wc * 64 + j * 16 + l16;
                float v = acc1[i][j][rr];
                if (EPI == 0) {
                    float u = acc2[i][j][rr];
                    float h = v / (1.f + __expf(-v)) * u;
                    ((unsigned short*)Cout)[orow * N + n] = f2bf(h);
                } else if (EPI == 1) {
                    ((float*)Cout)[orow * N + n] = v;
                } else {
                    atomicAdd(&((float*)Cout)[(size_t)tok * N + n], v * scl);
                }
            }
        }
    }
}

// ---------------- launch ----------------
extern "C" void kernel_launch(void* const* d_in, const int* in_sizes, int n_in,
                              void* d_out, int out_size, void* d_ws, size_t ws_size,
                              hipStream_t stream) {
    const float* x        = (const float*)d_in[0];
    const float* router_w = (const float*)d_in[1];
    const float* e_bias   = (const float*)d_in[2];
    const float* gate_w   = (const float*)d_in[3];
    const float* up_w     = (const float*)d_in[4];
    const float* down_w   = (const float*)d_in[5];
    const float* sh_gate  = (const float*)d_in[6];
    const float* sh_up    = (const float*)d_in[7];
    const float* sh_down  = (const float*)d_in[8];
    float* out = (float*)d_out;
    char* ws = (char*)d_ws;

    // ws layout (~261 MB)
    int*   counts    = (int*)(ws);
    int*   base      = (int*)(ws + 256);
    int*   cursor    = (int*)(ws + 512);
    int*   topk_idx  = (int*)(ws + 1024);
    float* topk_w    = (float*)(ws + 1024 + 131072);
    int*   row_token = (int*)(ws + 1024 + 2 * 131072);
    float* row_wgt   = (float*)(ws + 1024 + 3 * 131072);
    const size_t MB = 1u << 20;
    unsigned short* xb        = (unsigned short*)(ws + 1 * MB);    // 8 MB
    unsigned short* Hs        = (unsigned short*)(ws + 9 * MB);    // 16 MB
    unsigned short* Hr        = (unsigned short*)(ws + 25 * MB);   // 32 MB
    unsigned short* sh_gate_t = (unsigned short*)(ws + 57 * MB);   // 4 MB
    unsigned short* sh_up_t   = (unsigned short*)(ws + 61 * MB);   // 4 MB
    unsigned short* sh_down_t = (unsigned short*)(ws + 65 * MB);   // 4 MB
    unsigned short* gate_t    = (unsigned short*)(ws + 69 * MB);   // 64 MB
    unsigned short* up_t      = (unsigned short*)(ws + 133 * MB);  // 64 MB
    unsigned short* down_t    = (unsigned short*)(ws + 197 * MB);  // 64 MB -> 261 MB

    // ---- routing ----
    zero_counts_k<<<1, 64, 0, stream>>>(counts);
    router_k<<<S_TOK, 64, 0, stream>>>(x, router_w, e_bias, topk_idx, topk_w, counts);
    scan_k<<<1, 64, 0, stream>>>(counts, base, cursor);
    scatter_k<<<ROWS_TOTAL / 256, 256, 0, stream>>>(topk_idx, topk_w, cursor, row_token, row_wgt);

    // ---- prepass: bf16 conversion + weight transposes ----
    cvt_bf16_k<<<S_TOK * C_DIM / 8 / 256, 256, 0, stream>>>(x, xb, S_TOK * C_DIM / 8);
    transpose_k<<<dim3(HS_DIM / 64, C_DIM / 64, 1), 256, 0, stream>>>(sh_gate, sh_gate_t, C_DIM, HS_DIM);
    transpose_k<<<dim3(HS_DIM / 64, C_DIM / 64, 1), 256, 0, stream>>>(sh_up,   sh_up_t,   C_DIM, HS_DIM);
    transpose_k<<<dim3(C_DIM / 64, HS_DIM / 64, 1), 256, 0, stream>>>(sh_down, sh_down_t, HS_DIM, C_DIM);
    transpose_k<<<dim3(H_DIM / 64, C_DIM / 64, E_NUM), 256, 0, stream>>>(gate_w, gate_t, C_DIM, H_DIM);
    transpose_k<<<dim3(H_DIM / 64, C_DIM / 64, E_NUM), 256, 0, stream>>>(up_w,   up_t,   C_DIM, H_DIM);
    transpose_k<<<dim3(C_DIM / 64, H_DIM / 64, E_NUM), 256, 0, stream>>>(down_w, down_t, H_DIM, C_DIM);

    // ---- shared expert: fused gate+up+silu, then down (plain fp32 store) ----
    gemm2_k<true, false, false, 0><<<dim3(HS_DIM / 128, S_TOK / 128, 1), 256, 0, stream>>>(
        (const short*)xb, (const short*)sh_gate_t, (const short*)sh_up_t, Hs,
        S_TOK, HS_DIM, C_DIM, nullptr, nullptr, nullptr, nullptr);
    gemm2_k<false, false, false, 1><<<dim3(C_DIM / 128, S_TOK / 128, 1), 256, 0, stream>>>(
        (const short*)Hs, (const short*)sh_down_t, nullptr, out,
        S_TOK, C_DIM, HS_DIM, nullptr, nullptr, nullptr, nullptr);

    // ---- routed experts: fused gate+up+silu (gather), then down (atomic) ----
    gemm2_k<true, true, true, 0><<<dim3(H_DIM / 128, 32, E_NUM), 256, 0, stream>>>(
        (const short*)xb, (const short*)gate_t, (const short*)up_t, Hr,
        0, H_DIM, C_DIM, counts, base, row_token, row_wgt);
    gemm2_k<false, false, true, 2><<<dim3(C_DIM / 128, 32, E_NUM), 256, 0, stream>>>(
        (const short*)Hr, (const short*)down_t, nullptr, out,
        0, C_DIM, H_DIM, counts, base, row_token, row_wgt);
}

// Round 3
// 1018.421 us; speedup vs baseline: 1.9828x; 1.1644x over previous
//
#include <hip/hip_runtime.h>
#include <hip/hip_bf16.h>
#include <stdint.h>

// MoE FFN: sigmoid router (group-limited greedy top-8 of 64), SwiGLU experts
// (1024->512->1024) + shared expert (1024->2048->1024). All inputs fp32.
// R3: router rebuilt as fp32 tiled scores-GEMM + wave-parallel top-k
// (was 300us latency-bound one-wave-per-token kernel). GEMMs unchanged from
// R2 (m97 structure: global_load_lds w16, unpadded 64B LDS rows, ds_read_b128,
// 16x16x32 bf16 MFMA, gate+up+SiLU fused).

#define S_TOK 4096
#define C_DIM 1024
#define E_NUM 64
#define H_DIM 512
#define HS_DIM 2048
#define ROWS_TOTAL (S_TOK * 8)

typedef __attribute__((ext_vector_type(8))) short short8;
typedef __attribute__((ext_vector_type(4))) float f32x4;

static __device__ __forceinline__ unsigned short f2bf(float f) {
    union { float f; uint32_t u; } v; v.f = f;
    uint32_t u = v.u;
    u += 0x7fffu + ((u >> 16) & 1u);   // RNE
    return (unsigned short)(u >> 16);
}

static __device__ __forceinline__ void gl2lds16(const void* g, void* l) {
    __builtin_amdgcn_global_load_lds(
        (const __attribute__((address_space(1))) uint32_t*)g,
        (__attribute__((address_space(3))) uint32_t*)l, 16, 0, 0);
}

// ---------------- router part 1: scores = sigmoid(x @ rw^T), fp32 ----------------
// 32-token x 64-expert tile per block, BK=32, 2x4 register tile per thread.
__global__ __launch_bounds__(256)
void router_scores_k(const float* __restrict__ x, const float* __restrict__ rw,
                     float* __restrict__ scores) {
    int t0 = blockIdx.x * 32;
    __shared__ float xs[32][36];    // pad 36: float4-aligned rows
    __shared__ float wsm[64][36];
    int t = threadIdx.x;
    int tx = t & 15, ty = t >> 4;   // tx: 4-expert group, ty: 2-token group
    float acc[2][4] = {};
    for (int k0 = 0; k0 < C_DIM; k0 += 32) {
        {
            int r = t >> 3, c = t & 7;
            *(float4*)&xs[r][c * 4] = *(const float4*)(x + (size_t)(t0 + r) * C_DIM + k0 + c * 4);
        }
        #pragma unroll
        for (int i = 0; i < 2; i++) {
            int idx = t + 256 * i;
            int r = idx >> 3, c = idx & 7;
            *(float4*)&wsm[r][c * 4] = *(const float4*)(rw + (size_t)r * C_DIM + k0 + c * 4);
        }
        __syncthreads();
        #pragma unroll
        for (int kk = 0; kk < 32; kk += 4) {
            float4 a0 = *(const float4*)&xs[ty * 2 + 0][kk];
            float4 a1 = *(const float4*)&xs[ty * 2 + 1][kk];
            #pragma unroll
            for (int j = 0; j < 4; j++) {
                float4 b = *(const float4*)&wsm[tx * 4 + j][kk];
                acc[0][j] += a0.x * b.x + a0.y * b.y + a0.z * b.z + a0.w * b.w;
                acc[1][j] += a1.x * b.x + a1.y * b.y + a1.z * b.z + a1.w * b.w;
            }
        }
        __syncthreads();
    }
    #pragma unroll
    for (int i = 0; i < 2; i++)
        #pragma unroll
        for (int j = 0; j < 4; j++)
            scores[(size_t)(t0 + ty * 2 + i) * E_NUM + tx * 4 + j] =
                1.f / (1.f + __expf(-acc[i][j]));
}

// ---------------- router part 2: wave-parallel grouped top-k ----------------
// one wave per token (4 waves/block). lane = expert.
__global__ __launch_bounds__(256)
void topk_k(const float* __restrict__ scores, const float* __restrict__ ebias,
            int* __restrict__ topk_idx, float* __restrict__ topk_w,
            int* __restrict__ counts) {
    int t = blockIdx.x * 4 + (threadIdx.x >> 6);
    int e = threadIdx.x & 63;
    float sc = scores[(size_t)t * E_NUM + e];
    float sb = sc + ebias[e];
    // group-of-8 top-2 via xor-shuffle merges (exact max/min, no arithmetic)
    float m1 = sb, m2 = -1e30f;
    #pragma unroll
    for (int off = 1; off <= 4; off <<= 1) {
        float o1 = __shfl_xor(m1, off);
        float o2 = __shfl_xor(m2, off);
        float hi = fmaxf(m1, o1), lo = fminf(m1, o1);
        m2 = fmaxf(lo, fmaxf(m2, o2));
        m1 = hi;
    }
    float grp = m1 + m2;   // same add order as ref (top1 + top2)
    float grpv[8];
    #pragma unroll
    for (int g = 0; g < 8; g++) grpv[g] = __shfl(grp, g * 8);
    // top-4 groups, strict > ascending scan -> lowest index on ties (lax.top_k)
    unsigned gsel = 0;
    #pragma unroll
    for (int k = 0; k < 4; k++) {
        float best = -1e30f; int bi = 0;
        #pragma unroll
        for (int g = 0; g < 8; g++)
            if (!((gsel >> g) & 1) && grpv[g] > best) { best = grpv[g]; bi = g; }
        gsel |= 1u << bi;
    }
    // top-8 experts among selected groups: 8x wave argmax w/ lowest-index ties
    float val = ((gsel >> (e >> 3)) & 1) ? sb : -1e30f;
    int idx[8]; float sv[8]; float wsum = 0.f;
    #pragma unroll
    for (int k = 0; k < 8; k++) {
        uint32_t u = __float_as_uint(val);
        uint32_t mu = (u & 0x80000000u) ? ~u : (u | 0x80000000u);  // monotone map
        unsigned long long key = ((unsigned long long)mu << 6) | (unsigned long long)(63 - e);
        #pragma unroll
        for (int off = 32; off; off >>= 1) {
            unsigned long long ok = __shfl_xor(key, off);
            if (ok > key) key = ok;
        }
        int win = 63 - (int)(key & 63ull);
        idx[k] = win;
        sv[k] = __shfl(sc, win);
        wsum += sv[k];
        if (e == win) val = -1e30f;
    }
    float inv = 1.f / (wsum + 1e-20f);
    if (e < 8) {
        topk_idx[t * 8 + e] = idx[e];
        topk_w[t * 8 + e] = sv[e] * inv;
        atomicAdd(&counts[idx[e]], 1);
    }
}

__global__ void zero_counts_k(int* counts) { counts[threadIdx.x] = 0; }

__global__ void scan_k(const int* __restrict__ counts, int* __restrict__ base,
                       int* __restrict__ cursor) {
    if (threadIdx.x == 0) {
        int s = 0;
        for (int e = 0; e < E_NUM; e++) { base[e] = s; cursor[e] = s; s += counts[e]; }
    }
}

__global__ void scatter_k(const int* __restrict__ topk_idx, const float* __restrict__ topk_w,
                          int* __restrict__ cursor, int* __restrict__ row_token,
                          float* __restrict__ row_wgt) {
    int i = blockIdx.x * blockDim.x + threadIdx.x;
    int e = topk_idx[i];
    int pos = atomicAdd(&cursor[e], 1);
    row_token[pos] = i >> 3;
    row_wgt[pos] = topk_w[i];
}

// ---------------- prepass: fp32 -> bf16 elementwise (x) ----------------
__global__ void cvt_bf16_k(const float* __restrict__ in, unsigned short* __restrict__ out, int n8) {
    int i = blockIdx.x * blockDim.x + threadIdx.x;
    if (i >= n8) return;
    float4 v0 = ((const float4*)in)[2 * i];
    float4 v1 = ((const float4*)in)[2 * i + 1];
    unsigned short t[8] = { f2bf(v0.x), f2bf(v0.y), f2bf(v0.z), f2bf(v0.w),
                            f2bf(v1.x), f2bf(v1.y), f2bf(v1.z), f2bf(v1.w) };
    ((uint4*)out)[i] = *(uint4*)t;
}

// ---------------- prepass: fp32 [R][C] -> bf16 [C][R], batched over z ----------------
#define TP 69
__global__ __launch_bounds__(256)
void transpose_k(const float* __restrict__ in, unsigned short* __restrict__ out, int R, int C) {
    size_t bofs = (size_t)blockIdx.z * R * C;
    in += bofs; out += bofs;
    int r0 = blockIdx.y * 64, c0 = blockIdx.x * 64;
    __shared__ float T[64 * TP];
    int t = threadIdx.x;
    int cg = t & 15, rg = t >> 4;
    #pragma unroll
    for (int ii = 0; ii < 4; ii++) {
        float4 v = *(const float4*)(in + (size_t)(r0 + rg * 4 + ii) * C + c0 + cg * 4);
        T[(cg * 4 + 0) * TP + rg * 4 + ii] = v.x;
        T[(cg * 4 + 1) * TP + rg * 4 + ii] = v.y;
        T[(cg * 4 + 2) * TP + rg * 4 + ii] = v.z;
        T[(cg * 4 + 3) * TP + rg * 4 + ii] = v.w;
    }
    __syncthreads();
    int n = t >> 2, ks = (t & 3) * 16;
    unsigned short h[16];
    #pragma unroll
    for (int u = 0; u < 16; u++) h[u] = f2bf(T[n * TP + ks + u]);
    unsigned short* op = out + (size_t)(c0 + n) * R + r0 + ks;
    *(uint4*)op = *(uint4*)&h[0];
    *(uint4*)(op + 8) = *(uint4*)&h[8];
}

// ---------------- GEMM: C[M,N] = A[M,K] @ Bt[N,K]^T, bf16 in, fp32 acc ----------------
template<bool FUSED, bool GATHER, bool GROUPED, int EPI>
__global__ __launch_bounds__(256, 2)
void gemm2_k(const short* __restrict__ A, const short* __restrict__ B1t,
             const short* __restrict__ B2t, void* __restrict__ Cout,
             int M, int N, int K,
             const int* __restrict__ counts, const int* __restrict__ base,
             const int* __restrict__ row_token, const float* __restrict__ row_wgt) {
    int e = GROUPED ? blockIdx.z : 0;
    int Mrows = GROUPED ? counts[e] : M;
    int m0 = blockIdx.y * 128;
    if (m0 >= Mrows) return;
    int n0 = blockIdx.x * 128;
    int rowbase = GROUPED ? base[e] : 0;
    const short* B1 = B1t + (GROUPED ? (size_t)e * N * K : 0) + (size_t)n0 * K;
    const short* B2 = FUSED ? (B2t + (GROUPED ? (size_t)e * N * K : 0) + (size_t)n0 * K) : nullptr;

    __shared__ short As[128 * 32];
    __shared__ short Bs1[128 * 32];
    __shared__ short Bs2[FUSED ? 128 * 32 : 8];

    int tid = threadIdx.x;
    int lane = tid & 63, w = tid >> 6;
    int wr = w >> 1, wc = w & 1;
    int quad = lane >> 4, l16 = lane & 15;
    int sr = lane >> 2, sc = lane & 3;

    const short* aptr[2];
    const short* b1ptr[2];
    const short* b2ptr[2];
    #pragma unroll
    for (int i = 0; i < 2; i++) {
        int row = w * 32 + i * 16 + sr;
        int mrow = m0 + row;
        int cl = mrow < Mrows ? mrow : (Mrows - 1);
        size_t arow;
        if (GATHER)       arow = (size_t)row_token[rowbase + cl];
        else if (GROUPED) arow = (size_t)(rowbase + cl);
        else              arow = (size_t)mrow;
        aptr[i] = A + arow * K + sc * 8;
        b1ptr[i] = B1 + (size_t)row * K + sc * 8;
        if (FUSED) b2ptr[i] = B2 + (size_t)row * K + sc * 8;
    }

    f32x4 acc1[4][4] = {};
    f32x4 acc2[4][4] = {};

    for (int k0 = 0; k0 < K; k0 += 32) {
        #pragma unroll
        for (int i = 0; i < 2; i++) {
            int lb = (w * 32 + i * 16) * 32;
            gl2lds16(aptr[i], &As[lb]);   aptr[i] += 32;
            gl2lds16(b1ptr[i], &Bs1[lb]); b1ptr[i] += 32;
            if (FUSED) { gl2lds16(b2ptr[i], &Bs2[lb]); b2ptr[i] += 32; }
        }
        __syncthreads();
        short8 a[4], b1[4], b2[4];
        #pragma unroll
        for (int i = 0; i < 4; i++)
            a[i] = *(const short8*)&As[(wr * 64 + i * 16 + l16) * 32 + quad * 8];
        #pragma unroll
        for (int j = 0; j < 4; j++) {
            b1[j] = *(const short8*)&Bs1[(wc * 64 + j * 16 + l16) * 32 + quad * 8];
            if (FUSED)
                b2[j] = *(const short8*)&Bs2[(wc * 64 + j * 16 + l16) * 32 + quad * 8];
        }
        #pragma unroll
        for (int i = 0; i < 4; i++)
            #pragma unroll
            for (int j = 0; j < 4; j++) {
                acc1[i][j] = __builtin_amdgcn_mfma_f32_16x16x32_bf16(a[i], b1[j], acc1[i][j], 0, 0, 0);
                if (FUSED)
                    acc2[i][j] = __builtin_amdgcn_mfma_f32_16x16x32_bf16(a[i], b2[j], acc2[i][j], 0, 0, 0);
            }
        __syncthreads();
    }

    #pragma unroll
    for (int i = 0; i < 4; i++) {
        #pragma unroll
        for (int rr = 0; rr < 4; rr++) {
            int row = m0 + wr * 64 + i * 16 + quad * 4 + rr;
            if (row >= Mrows) continue;
            size_t orow = GROUPED ? (size_t)(rowbase + row) : (size_t)row;
            int tok = 0; float scl = 0.f;
            if (EPI == 2) { tok = row_token[rowbase + row]; scl = row_wgt[rowbase + row]; }
            #pragma unroll
            for (int j = 0; j < 4; j++) {
                int n = n0 + wc * 64 + j * 16 + l16;
                float v = acc1[i][j][rr];
                if (EPI == 0) {
                    float u = acc2[i][j][rr];
                    float h = v / (1.f + __expf(-v)) * u;
                    ((unsigned short*)Cout)[orow * N + n] = f2bf(h);
                } else if (EPI == 1) {
                    ((float*)Cout)[orow * N + n] = v;
                } else {
                    atomicAdd(&((float*)Cout)[(size_t)tok * N + n], v * scl);
                }
            }
        }
    }
}

// ---------------- launch ----------------
extern "C" void kernel_launch(void* const* d_in, const int* in_sizes, int n_in,
                              void* d_out, int out_size, void* d_ws, size_t ws_size,
                              hipStream_t stream) {
    const float* x        = (const float*)d_in[0];
    const float* router_w = (const float*)d_in[1];
    const float* e_bias   = (const float*)d_in[2];
    const float* gate_w   = (const float*)d_in[3];
    const float* up_w     = (const float*)d_in[4];
    const float* down_w   = (const float*)d_in[5];
    const float* sh_gate  = (const float*)d_in[6];
    const float* sh_up    = (const float*)d_in[7];
    const float* sh_down  = (const float*)d_in[8];
    float* out = (float*)d_out;
    char* ws = (char*)d_ws;

    int*   counts    = (int*)(ws);
    int*   base      = (int*)(ws + 256);
    int*   cursor    = (int*)(ws + 512);
    int*   topk_idx  = (int*)(ws + 1024);
    float* topk_w    = (float*)(ws + 1024 + 131072);
    int*   row_token = (int*)(ws + 1024 + 2 * 131072);
    float* row_wgt   = (float*)(ws + 1024 + 3 * 131072);
    float* scoresbuf = (float*)(ws + 1024 + 4 * 131072);           // 1 MB
    const size_t MB = 1u << 20;
    unsigned short* xb        = (unsigned short*)(ws + 2 * MB);    // 8 MB
    unsigned short* Hs        = (unsigned short*)(ws + 10 * MB);   // 16 MB
    unsigned short* Hr        = (unsigned short*)(ws + 26 * MB);   // 32 MB
    unsigned short* sh_gate_t = (unsigned short*)(ws + 58 * MB);   // 4 MB
    unsigned short* sh_up_t   = (unsigned short*)(ws + 62 * MB);   // 4 MB
    unsigned short* sh_down_t = (unsigned short*)(ws + 66 * MB);   // 4 MB
    unsigned short* gate_t    = (unsigned short*)(ws + 70 * MB);   // 64 MB
    unsigned short* up_t      = (unsigned short*)(ws + 134 * MB);  // 64 MB
    unsigned short* down_t    = (unsigned short*)(ws + 198 * MB);  // 64 MB -> 262 MB

    // ---- routing ----
    zero_counts_k<<<1, 64, 0, stream>>>(counts);
    router_scores_k<<<S_TOK / 32, 256, 0, stream>>>(x, router_w, scoresbuf);
    topk_k<<<S_TOK / 4, 256, 0, stream>>>(scoresbuf, e_bias, topk_idx, topk_w, counts);
    scan_k<<<1, 64, 0, stream>>>(counts, base, cursor);
    scatter_k<<<ROWS_TOTAL / 256, 256, 0, stream>>>(topk_idx, topk_w, cursor, row_token, row_wgt);

    // ---- prepass: bf16 conversion + weight transposes ----
    cvt_bf16_k<<<S_TOK * C_DIM / 8 / 256, 256, 0, stream>>>(x, xb, S_TOK * C_DIM / 8);
    transpose_k<<<dim3(HS_DIM / 64, C_DIM / 64, 1), 256, 0, stream>>>(sh_gate, sh_gate_t, C_DIM, HS_DIM);
    transpose_k<<<dim3(HS_DIM / 64, C_DIM / 64, 1), 256, 0, stream>>>(sh_up,   sh_up_t,   C_DIM, HS_DIM);
    transpose_k<<<dim3(C_DIM / 64, HS_DIM / 64, 1), 256, 0, stream>>>(sh_down, sh_down_t, HS_DIM, C_DIM);
    transpose_k<<<dim3(H_DIM / 64, C_DIM / 64, E_NUM), 256, 0, stream>>>(gate_w, gate_t, C_DIM, H_DIM);
    transpose_k<<<dim3(H_DIM / 64, C_DIM / 64, E_NUM), 256, 0, stream>>>(up_w,   up_t,   C_DIM, H_DIM);
    transpose_k<<<dim3(C_DIM / 64, H_DIM / 64, E_NUM), 256, 0, stream>>>(down_w, down_t, H_DIM, C_DIM);

    // ---- shared expert ----
    gemm2_k<true, false, false, 0><<<dim3(HS_DIM / 128, S_TOK / 128, 1), 256, 0, stream>>>(
        (const short*)xb, (const short*)sh_gate_t, (const short*)sh_up_t, Hs,
        S_TOK, HS_DIM, C_DIM, nullptr, nullptr, nullptr, nullptr);
    gemm2_k<false, false, false, 1><<<dim3(C_DIM / 128, S_TOK / 128, 1), 256, 0, stream>>>(
        (const short*)Hs, (const short*)sh_down_t, nullptr, out,
        S_TOK, C_DIM, HS_DIM, nullptr, nullptr, nullptr, nullptr);

    // ---- routed experts ----
    gemm2_k<true, true, true, 0><<<dim3(H_DIM / 128, 32, E_NUM), 256, 0, stream>>>(
        (const short*)xb, (const short*)gate_t, (const short*)up_t, Hr,
        0, H_DIM, C_DIM, counts, base, row_token, row_wgt);
    gemm2_k<false, false, true, 2><<<dim3(C_DIM / 128, 32, E_NUM), 256, 0, stream>>>(
        (const short*)Hr, (const short*)down_t, nullptr, out,
        0, C_DIM, H_DIM, counts, base, row_token, row_wgt);
}